// Round 6
// baseline (147.531 us; speedup 1.0000x reference)
//
#include <hip/hip_runtime.h>

constexpr int kC = 147, kH = 64, kBPM = 32;

typedef __attribute__((ext_vector_type(8)))  short bf16x8;   // MFMA A/B frag
typedef __attribute__((ext_vector_type(4)))  float f32x4;    // 16x16 C/D frag
typedef __attribute__((ext_vector_type(16))) float f32x16;   // 32x32 C/D frag
typedef __attribute__((ext_vector_type(2)))  unsigned u32x2;
typedef __attribute__((ext_vector_type(4)))  unsigned u32x4;

__device__ __forceinline__ short f2bf(float f) {             // RNE float->bf16
    unsigned u = __builtin_bit_cast(unsigned, f);
    u += 0x7fffu + ((u >> 16) & 1u);
    return (short)(u >> 16);
}
// Packed RNE f32x2 -> bf16x2 (single VALU op; bit-identical to f2bf pairs).
__device__ __forceinline__ unsigned cvt_pk(float lo, float hi) {
    unsigned r;
    asm("v_cvt_pk_bf16_f32 %0, %1, %2" : "=v"(r) : "v"(lo), "v"(hi));
    return r;
}
#define MFMA16(a,b,c) __builtin_amdgcn_mfma_f32_16x16x32_bf16((a),(b),(c),0,0,0)
#define MFMA32(a,b,c) __builtin_amdgcn_mfma_f32_32x32x16_bf16((a),(b),(c),0,0,0)

// Softmax in base 2: Wq and q-bias pre-scaled by 0.25*log2(e); P = 2^s.
#if __has_builtin(__builtin_amdgcn_exp2f)
  #define EXP2(x) __builtin_amdgcn_exp2f(x)
#else
  #define EXP2(x) __expf((x) * 0.6931471805599453f)   // exact: e^(x ln2) = 2^x
#endif
constexpr float kQScale = 0.25f * 1.4426950408889634f;

// LDS strides (shorts); all rows 16B-aligned.
constexpr int QS  = 72;    // qs/ks row stride
constexpr int VS  = 264;   // vt row stride
constexpr int PS  = 40;    // per-wave P^T scratch row stride (XOR-swizzled cols)
constexpr int WSS = 168;   // Ws qkv: [c][k], k padded to 160 (XOR-swizzled k)
constexpr int WOS = 72;    // Ws oproj: [n][k], k=64 (XOR-swizzled k)

// LDS write-out of a prefetched W (values already scaled at load time).
// Thread map matches the coalesced load map: c = i&63, k-pair = i>>6.
__device__ __forceinline__ void stage_w_regs(const float* wr /*10*/,
                                             short* Ws, int tid) {
    #pragma unroll
    for (int it = 0; it < 5; ++it) {
        const int i = it * 1024 + tid;          // 5120 = 64c x 80 k-pairs
        const int c = i & 63, k = (i >> 6) * 2;
        *(unsigned*)&Ws[c * WSS + (k ^ (((c >> 3) & 3) << 3))]
            = cvt_pk(wr[2*it], wr[2*it + 1]);
    }
}

// One block per batch: 1024 threads = 16 waves = 4 waves/SIMD; LDS 151.8 KB.
__global__ __launch_bounds__(1024, 4) void fused_kernel(
    const float* __restrict__ pose, const float* __restrict__ bpm_emb,
    const float* __restrict__ Wq, const float* __restrict__ bq,
    const float* __restrict__ Wk, const float* __restrict__ bk,
    const float* __restrict__ Wv, const float* __restrict__ bv,
    const float* __restrict__ Wb, const float* __restrict__ bb,
    const float* __restrict__ Wo, const float* __restrict__ bo,
    float* __restrict__ out)
{
    __shared__ __align__(16) short qs[256 * QS];    // q, later attn-out X  36.9 KB
    __shared__ __align__(16) short ks_[256 * QS];   // k (+bpm bias)        36.9 KB
    __shared__ __align__(16) short vt[kH * VS];     // V^T: [h*16+d][j]     33.8 KB
    __shared__ __align__(16) short WsPt[21504];     // WsA|WsB dbuf ∪ Pt ∪ Wo  43 KB
    __shared__ float l_s[16 * 64];                  // per-wave row-sums     4.0 KB
    __shared__ float bias_s[192];
    short* const WsA = WsPt;                        // [0, 10752)
    short* const WsB = WsPt + 10752;                // [10752, 21504)
    short* const Pt  = WsPt;                        // attn scratch (20480 shorts)
    short* const Ws  = WsPt;                        // Wo region (11520 shorts)

    const int tid = threadIdx.x;
    const int w = tid >> 6, lane = tid & 63;
    const int ll = lane & 15, lq = lane >> 4;
    const int lm = lane & 31, lh = lane >> 5;
    const int b = blockIdx.x;
    const size_t pbase = (size_t)b * 256 * kC;

    // ---- pose B-frags FIRST (block-exclusive data: start HBM latency now) --
    bf16x8 pf[5];
    {
        const int row = w * 16 + ll;
        const float* prow = pose + pbase + (size_t)row * kC;
        #pragma unroll
        for (int ksp = 0; ksp < 5; ++ksp) {
            const int c0 = ksp * 32 + lq * 8;
            float v[8];
            if (c0 + 8 <= kC) {
                const float4 f0 = *(const float4*)(prow + c0);
                const float4 f1 = *(const float4*)(prow + c0 + 4);
                v[0]=f0.x; v[1]=f0.y; v[2]=f0.z; v[3]=f0.w;
                v[4]=f1.x; v[5]=f1.y; v[6]=f1.z; v[7]=f1.w;
            } else {
                #pragma unroll
                for (int e = 0; e < 8; ++e) v[e] = (c0 + e < kC) ? prow[c0 + e] : 0.f;
            }
            const u32x4 t = { cvt_pk(v[0], v[1]), cvt_pk(v[2], v[3]),
                              cvt_pk(v[4], v[5]), cvt_pk(v[6], v[7]) };
            pf[ksp] = __builtin_bit_cast(bf16x8, t);
        }
    }
    // ---- Wq -> regs (L2/L3-shared; in flight under bias compute) ----
    float wq_r[10];
    #pragma unroll
    for (int it = 0; it < 5; ++it) {
        const int i = it * 1024 + tid;
        const int c = i & 63, k = (i >> 6) * 2;
        wq_r[2*it]   = (k     < kC) ? Wq[k * kH + c] * kQScale : 0.f;
        wq_r[2*it+1] = (k + 1 < kC) ? Wq[(k + 1) * kH + c] * kQScale : 0.f;
    }
    // ---- combined biases (q-bias pre-scaled by kQScale) ----
    if (tid < 192) {
        const int m = tid >> 6, c = tid & 63;
        float a = ((m == 0) ? bq : (m == 1) ? bk : bv)[c];
        if (m == 1) {
            a += bb[c];
            #pragma unroll
            for (int k2 = 0; k2 < kBPM; ++k2)
                a = fmaf(bpm_emb[b * kBPM + k2], Wb[k2 * kH + c], a);
        }
        if (m == 0) a *= kQScale;
        bias_s[tid] = a;
    }
    stage_w_regs(wq_r, WsA, tid);
    __syncthreads();

    // ================= QKV: wave = 16 pose rows, A = W^T (M=64 cols) =======
    // Double-buffered Ws (disjoint halves of WsPt): round m reads one half
    // while staging the next W into the other -> ONE barrier per round.
    auto qkv_mfma = [&](const short* R, f32x4 (&acc)[4]) {
        #pragma unroll
        for (int mt = 0; mt < 4; ++mt) acc[mt] = (f32x4){0.f,0.f,0.f,0.f};
        #pragma unroll
        for (int ksp = 0; ksp < 5; ++ksp)
            #pragma unroll
            for (int mt = 0; mt < 4; ++mt) {
                const int c = mt * 16 + ll;
                const int key = ((c >> 3) & 3) << 3;
                const bf16x8 wf = *(const bf16x8*)(R + c * WSS + ((ksp*32 + lq*8) ^ key));
                acc[mt] = MFMA16(wf, pf[ksp], acc[mt]);
            }
    };
    auto qkv_epi = [&](const f32x4 (&acc)[4], int m) {
        // epilogue: D row = out-col mt*16+4lq+r, D col = pose-row w*16+ll
        const int row = w * 16 + ll;
        #pragma unroll
        for (int mt = 0; mt < 4; ++mt) {
            const int c0 = mt * 16 + 4 * lq;
            const float4 bv4 = *(const float4*)&bias_s[m * kH + c0];
            if (m < 2) {
                const u32x2 pk = { cvt_pk(acc[mt][0] + bv4.x, acc[mt][1] + bv4.y),
                                   cvt_pk(acc[mt][2] + bv4.z, acc[mt][3] + bv4.w) };
                *(u32x2*)((m == 0 ? qs : ks_) + row * QS + c0) = pk;
            } else {                            // V stored transposed: vt[c][row]
                vt[(c0 + 0) * VS + row] = f2bf(acc[mt][0] + bv4.x);
                vt[(c0 + 1) * VS + row] = f2bf(acc[mt][1] + bv4.y);
                vt[(c0 + 2) * VS + row] = f2bf(acc[mt][2] + bv4.z);
                vt[(c0 + 3) * VS + row] = f2bf(acc[mt][3] + bv4.w);
            }
        }
    };

    // ---- m=0: Q (reads WsA). JIT-load Wk; stage into WsB during compute. ----
    {
        float wk_r[10];
        #pragma unroll
        for (int it = 0; it < 5; ++it) {
            const int i = it * 1024 + tid;
            const int c = i & 63, k = (i >> 6) * 2;
            wk_r[2*it]   = (k     < kC) ? Wk[k * kH + c] : 0.f;
            wk_r[2*it+1] = (k + 1 < kC) ? Wk[(k + 1) * kH + c] : 0.f;
        }
        f32x4 acc[4];
        qkv_mfma(WsA, acc);
        stage_w_regs(wk_r, WsB, tid);           // disjoint from WsA: no barrier
        // JIT-load Wv now: in flight across epilogue + barrier + m=1 MFMAs
        float wv_r[10];
        #pragma unroll
        for (int it = 0; it < 5; ++it) {
            const int i = it * 1024 + tid;
            const int c = i & 63, k = (i >> 6) * 2;
            wv_r[2*it]   = (k     < kC) ? Wv[k * kH + c] : 0.f;
            wv_r[2*it+1] = (k + 1 < kC) ? Wv[(k + 1) * kH + c] : 0.f;
        }
        qkv_epi(acc, 0);
        __syncthreads();                        // WsB (Wk) ready for all

        // ---- m=1: K (reads WsB); stage Wv into WsA during compute. ----
        f32x4 acc1[4];
        qkv_mfma(WsB, acc1);
        stage_w_regs(wv_r, WsA, tid);
        qkv_epi(acc1, 1);
        __syncthreads();                        // WsA (Wv) ready
    }
    // ---- m=2: V (reads WsA). ----
    {
        f32x4 acc[4];
        qkv_mfma(WsA, acc);
        qkv_epi(acc, 2);
        __syncthreads();                        // q/k/vt complete; Ws dead -> Pt
    }

    // ================= attention: wave = (head, q-quarter of 64) ===========
    const int h = w & 3;
    const int q0 = (w >> 2) * 64;
    bf16x8 qf[2];                              // B-frags (read own q region)
    #pragma unroll
    for (int s32 = 0; s32 < 2; ++s32)
        qf[s32] = *(const bf16x8*)(qs + (q0 + s32*32 + lm) * QS + h*16 + lh*8);

    // ---- T14: prefetch Wo into regs now; consumed ~2000 cy later ----
    float wo_r[10];
    #pragma unroll
    for (int it = 0; it < 5; ++it) {
        const int i = it * 1024 + tid;          // 5120 = 160n x 32 k-pairs
        const int n = i % 160, k = (i / 160) * 2;
        wo_r[2*it]   = (n < kC) ? Wo[k * kC + n] : 0.f;
        wo_r[2*it+1] = (n < kC) ? Wo[(k + 1) * kC + n] : 0.f;
    }

    f32x4 oacc[2][2];
    #pragma unroll
    for (int s32 = 0; s32 < 2; ++s32) {
        oacc[s32][0] = (f32x4){0.f,0.f,0.f,0.f};
        oacc[s32][1] = (f32x4){0.f,0.f,0.f,0.f};
    }
    float lp[2] = {0.f, 0.f};
    short* Pw = Pt + w * 32 * PS;
    const int wkey = ((lm >> 3) & 3) << 3;     // P write-side XOR key (per q'=lm)

    #pragma unroll 2
    for (int jb = 0; jb < 8; ++jb) {
        const int j0 = jb * 32;
        const bf16x8 kf = *(const bf16x8*)(ks_ + (j0 + lm) * QS + h*16 + lh*8);
        const bf16x8 vf = *(const bf16x8*)(vt + (h*16 + ll) * VS + j0 + lq*8);
        #pragma unroll
        for (int s32 = 0; s32 < 2; ++s32) {
            const f32x16 z16 = {0.f,0.f,0.f,0.f,0.f,0.f,0.f,0.f,
                                0.f,0.f,0.f,0.f,0.f,0.f,0.f,0.f};
            const f32x16 s = MFMA32(kf, qf[s32], z16);   // S^T: col=q=lm, row=j
            float sum = 0.f;
            #pragma unroll
            for (int g = 0; g < 4; ++g) {                // j = r + 8g + 4lh
                const float p0 = EXP2(s[4*g + 0]);       // scale folded into Wq
                const float p1 = EXP2(s[4*g + 1]);
                const float p2 = EXP2(s[4*g + 2]);
                const float p3 = EXP2(s[4*g + 3]);
                sum += (p0 + p1) + (p2 + p3);
                const u32x2 pk = { cvt_pk(p0, p1), cvt_pk(p2, p3) };
                *(u32x2*)(Pw + lm * PS + ((8*g + 4*lh) ^ wkey)) = pk;
            }
            lp[s32] += sum;
            #pragma unroll
            for (int half = 0; half < 2; ++half) {       // O^T += V^T . P^T
                const int qp = half * 16 + ll;
                const int rkey = ((qp >> 3) & 3) << 3;
                const bf16x8 pfr = *(const bf16x8*)(Pw + qp * PS + ((lq*8) ^ rkey));
                oacc[s32][half] = MFMA16(vf, pfr, oacc[s32][half]);
            }
        }
    }
    #pragma unroll
    for (int s32 = 0; s32 < 2; ++s32) {
        const float l2 = lp[s32] + __shfl_xor(lp[s32], 32);
        if (lane < 32) l_s[w * 64 + s32 * 32 + lm] = l2;
    }
    #pragma unroll
    for (int s32 = 0; s32 < 2; ++s32)
        #pragma unroll
        for (int half = 0; half < 2; ++half) {
            const int qi = s32 * 32 + half * 16 + ll;
            const float inv = 1.f / l_s[w * 64 + qi];
            // X[q0+qi][h*16 + 4lq + r] — wave-private (row,col) tile
            const u32x2 pk = { cvt_pk(oacc[s32][half][0] * inv, oacc[s32][half][1] * inv),
                               cvt_pk(oacc[s32][half][2] * inv, oacc[s32][half][3] * inv) };
            *(u32x2*)(qs + (q0 + qi) * QS + h*16 + 4*lq) = pk;
        }
    __syncthreads();                            // Pt dead, X complete

    // ---- stage Wot[n][k] into Ws from regs (overwrites Pt) ----
    #pragma unroll
    for (int it = 0; it < 5; ++it) {
        const int i = it * 1024 + tid;
        const int n = i % 160, k = (i / 160) * 2;
        *(unsigned*)&Ws[n * WOS + (k ^ (((n >> 3) & 3) << 3))]
            = cvt_pk(wo_r[2*it], wo_r[2*it + 1]);
    }
    __syncthreads();

    // ================= output projection: X[256x64] @ Wo + bo ==============
    bf16x8 xf[2];
    #pragma unroll
    for (int k2 = 0; k2 < 2; ++k2)
        xf[k2] = *(const bf16x8*)(qs + (w*16 + ll) * QS + k2*32 + lq*8);

    f32x4 po[10];
    #pragma unroll
    for (int mt = 0; mt < 10; ++mt) po[mt] = (f32x4){0.f,0.f,0.f,0.f};
    #pragma unroll
    for (int k2 = 0; k2 < 2; ++k2)
        #pragma unroll
        for (int mt = 0; mt < 10; ++mt) {
            const int n = mt * 16 + ll;
            const int key = ((n >> 3) & 3) << 3;
            const bf16x8 wf = *(const bf16x8*)(Ws + n * WOS + ((k2*32 + lq*8) ^ key));
            po[mt] = MFMA16(wf, xf[k2], po[mt]);
        }
    {
        const int row = w * 16 + ll;
        float* orow = out + ((size_t)b * 256 + row) * kC;
        #pragma unroll
        for (int mt = 0; mt < 10; ++mt) {
            const int c0 = mt * 16 + 4 * lq;
            if (mt < 9) {
                const float4 bv4 = *(const float4*)(bo + c0);
                float4 o;
                o.x = po[mt][0] + bv4.x; o.y = po[mt][1] + bv4.y;
                o.z = po[mt][2] + bv4.z; o.w = po[mt][3] + bv4.w;
                *(float4*)(orow + c0) = o;
            } else {
                #pragma unroll
                for (int r = 0; r < 4; ++r) {
                    const int c = c0 + r;
                    if (c < kC) orow[c] = po[mt][r] + bo[c];
                }
            }
        }
    }
}

extern "C" void kernel_launch(void* const* d_in, const int* in_sizes, int n_in,
                              void* d_out, int out_size, void* d_ws, size_t ws_size,
                              hipStream_t stream) {
    const float* pose    = (const float*)d_in[0];
    const float* bpm_emb = (const float*)d_in[1];
    const float* Wq = (const float*)d_in[2];  const float* bq = (const float*)d_in[3];
    const float* Wk = (const float*)d_in[4];  const float* bk = (const float*)d_in[5];
    const float* Wv = (const float*)d_in[6];  const float* bv = (const float*)d_in[7];
    const float* Wb = (const float*)d_in[8];  const float* bb = (const float*)d_in[9];
    const float* Wo = (const float*)d_in[10]; const float* bo = (const float*)d_in[11];
    float* out = (float*)d_out;

    fused_kernel<<<256, 1024, 0, stream>>>(
        pose, bpm_emb, Wq, bq, Wk, bk, Wv, bv, Wb, bb, Wo, bo, out);
}

// Round 7
// 130.034 us; speedup vs baseline: 1.1346x; 1.1346x over previous
//
#include <hip/hip_runtime.h>

constexpr int kC = 147, kH = 64, kBPM = 32;

typedef __attribute__((ext_vector_type(8)))  short bf16x8;   // MFMA A/B frag
typedef __attribute__((ext_vector_type(4)))  float f32x4;    // 16x16 C/D frag
typedef __attribute__((ext_vector_type(16))) float f32x16;   // 32x32 C/D frag
typedef __attribute__((ext_vector_type(2)))  unsigned u32x2;
typedef __attribute__((ext_vector_type(4)))  unsigned u32x4;

__device__ __forceinline__ short f2bf(float f) {             // RNE float->bf16
    unsigned u = __builtin_bit_cast(unsigned, f);
    u += 0x7fffu + ((u >> 16) & 1u);
    return (short)(u >> 16);
}
// Packed RNE f32x2 -> bf16x2 (single VALU op; bit-identical to f2bf pairs).
__device__ __forceinline__ unsigned cvt_pk(float lo, float hi) {
    unsigned r;
    asm("v_cvt_pk_bf16_f32 %0, %1, %2" : "=v"(r) : "v"(lo), "v"(hi));
    return r;
}
#define MFMA16(a,b,c) __builtin_amdgcn_mfma_f32_16x16x32_bf16((a),(b),(c),0,0,0)
#define MFMA32(a,b,c) __builtin_amdgcn_mfma_f32_32x32x16_bf16((a),(b),(c),0,0,0)

// Softmax in base 2: Wq and q-bias pre-scaled by 0.25*log2(e); P = 2^s.
#if __has_builtin(__builtin_amdgcn_exp2f)
  #define EXP2(x) __builtin_amdgcn_exp2f(x)
#else
  #define EXP2(x) __expf((x) * 0.6931471805599453f)   // exact: e^(x ln2) = 2^x
#endif
constexpr float kQScale = 0.25f * 1.4426950408889634f;

// LDS strides (shorts); all rows 16B-aligned.
constexpr int QS  = 72;    // qs/ks row stride
constexpr int VS  = 264;   // vt row stride
constexpr int WSS = 168;   // Ws qkv: [c][k], k padded to 160 (XOR-swizzled k)
constexpr int WOS = 72;    // Ws oproj: [n][k], k=64 (XOR-swizzled k)

// LDS write-out of a prefetched W (values already scaled at load time).
// Thread map matches the coalesced load map: c = i&63, k-pair = i>>6.
__device__ __forceinline__ void stage_w_regs(const float* wr /*10*/,
                                             short* Ws, int tid) {
    #pragma unroll
    for (int it = 0; it < 5; ++it) {
        const int i = it * 1024 + tid;          // 5120 = 64c x 80 k-pairs
        const int c = i & 63, k = (i >> 6) * 2;
        *(unsigned*)&Ws[c * WSS + (k ^ (((c >> 3) & 3) << 3))]
            = cvt_pk(wr[2*it], wr[2*it + 1]);
    }
}

// QKV MFMA block (macro, not lambda: array-by-ref lambdas risk scratch).
#define QKV_MFMA(Rbuf)                                                        \
    {                                                                         \
        _Pragma("unroll")                                                     \
        for (int mt = 0; mt < 4; ++mt) acc[mt] = (f32x4){0.f,0.f,0.f,0.f};    \
        _Pragma("unroll")                                                     \
        for (int ksp = 0; ksp < 5; ++ksp)                                     \
            _Pragma("unroll")                                                 \
            for (int mt = 0; mt < 4; ++mt) {                                  \
                const int c = mt * 16 + ll;                                   \
                const int key = ((c >> 3) & 3) << 3;                          \
                const bf16x8 wf = *(const bf16x8*)((Rbuf) + c * WSS +         \
                                      ((ksp * 32 + lq * 8) ^ key));           \
                acc[mt] = MFMA16(wf, pf[ksp], acc[mt]);                       \
            }                                                                 \
    }

// One block per batch: 1024 threads = 16 waves = 4 waves/SIMD (LDS-capped at
// 1 block/CU).  amdgpu_waves_per_eu(4,4) pins the compiler to that occupancy
// so the VGPR budget is 128/wave (observed heuristic otherwise caps at 64 and
// spills to scratch: R4/R5/R6 FETCH/WRITE inflation).
__global__ __launch_bounds__(1024)
__attribute__((amdgpu_waves_per_eu(4, 4)))
void fused_kernel(
    const float* __restrict__ pose, const float* __restrict__ bpm_emb,
    const float* __restrict__ Wq, const float* __restrict__ bq,
    const float* __restrict__ Wk, const float* __restrict__ bk,
    const float* __restrict__ Wv, const float* __restrict__ bv,
    const float* __restrict__ Wb, const float* __restrict__ bb,
    const float* __restrict__ Wo, const float* __restrict__ bo,
    float* __restrict__ out)
{
    __shared__ __align__(16) short qs[256 * QS];    // q, later attn-out X  36.9 KB
    __shared__ __align__(16) short ks_[256 * QS];   // k (+bpm bias)        36.9 KB
    __shared__ __align__(16) short vt[kH * VS];     // V^T: [h*16+d][j]     33.8 KB
    __shared__ __align__(16) short WsA[11520];      // Wq, then Wv          23.0 KB
    __shared__ __align__(16) short WsB[11520];      // Wk, then Wo          23.0 KB
    __shared__ float bias_s[192];

    const int tid = threadIdx.x;
    const int w = tid >> 6, lane = tid & 63;
    const int ll = lane & 15, lq = lane >> 4;
    const int lm = lane & 31, lh = lane >> 5;
    const int b = blockIdx.x;
    const size_t pbase = (size_t)b * 256 * kC;

    // ---- pose B-frags FIRST (block-exclusive data: start HBM latency now) --
    bf16x8 pf[5];
    {
        const int row = w * 16 + ll;
        const float* prow = pose + pbase + (size_t)row * kC;
        #pragma unroll
        for (int ksp = 0; ksp < 5; ++ksp) {
            const int c0 = ksp * 32 + lq * 8;
            float v[8];
            if (c0 + 8 <= kC) {
                const float4 f0 = *(const float4*)(prow + c0);
                const float4 f1 = *(const float4*)(prow + c0 + 4);
                v[0]=f0.x; v[1]=f0.y; v[2]=f0.z; v[3]=f0.w;
                v[4]=f1.x; v[5]=f1.y; v[6]=f1.z; v[7]=f1.w;
            } else {
                #pragma unroll
                for (int e = 0; e < 8; ++e) v[e] = (c0 + e < kC) ? prow[c0 + e] : 0.f;
            }
            const u32x4 t = { cvt_pk(v[0], v[1]), cvt_pk(v[2], v[3]),
                              cvt_pk(v[4], v[5]), cvt_pk(v[6], v[7]) };
            pf[ksp] = __builtin_bit_cast(bf16x8, t);
        }
    }
    // ---- Wq -> regs (L2/L3-shared; in flight under bias compute) ----
    float wq_r[10];
    #pragma unroll
    for (int it = 0; it < 5; ++it) {
        const int i = it * 1024 + tid;
        const int c = i & 63, k = (i >> 6) * 2;
        wq_r[2*it]   = (k     < kC) ? Wq[k * kH + c] * kQScale : 0.f;
        wq_r[2*it+1] = (k + 1 < kC) ? Wq[(k + 1) * kH + c] * kQScale : 0.f;
    }
    // ---- combined biases (q-bias pre-scaled by kQScale) ----
    if (tid < 192) {
        const int m = tid >> 6, c = tid & 63;
        float a = ((m == 0) ? bq : (m == 1) ? bk : bv)[c];
        if (m == 1) {
            a += bb[c];
            #pragma unroll
            for (int k2 = 0; k2 < kBPM; ++k2)
                a = fmaf(bpm_emb[b * kBPM + k2], Wb[k2 * kH + c], a);
        }
        if (m == 0) a *= kQScale;
        bias_s[tid] = a;
    }
    stage_w_regs(wq_r, WsA, tid);
    __syncthreads();

    // ================= QKV: wave = 16 pose rows, A = W^T (M=64 cols) =======
    // Double-buffered Ws (separate __shared__ arrays): round m reads one
    // buffer while staging the next W into the other -> ONE barrier per round.
    // ---- m=0: Q (reads WsA); JIT-load Wk, stage into WsB during compute ----
    {
        float wk_r[10];
        #pragma unroll
        for (int it = 0; it < 5; ++it) {
            const int i = it * 1024 + tid;
            const int c = i & 63, k = (i >> 6) * 2;
            wk_r[2*it]   = (k     < kC) ? Wk[k * kH + c] : 0.f;
            wk_r[2*it+1] = (k + 1 < kC) ? Wk[(k + 1) * kH + c] : 0.f;
        }
        f32x4 acc[4];
        QKV_MFMA(WsA);
        stage_w_regs(wk_r, WsB, tid);           // disjoint from WsA: no barrier
        // JIT-load Wv: in flight across epilogue + barrier + m=1 MFMAs
        float wv_r[10];
        #pragma unroll
        for (int it = 0; it < 5; ++it) {
            const int i = it * 1024 + tid;
            const int c = i & 63, k = (i >> 6) * 2;
            wv_r[2*it]   = (k     < kC) ? Wv[k * kH + c] : 0.f;
            wv_r[2*it+1] = (k + 1 < kC) ? Wv[(k + 1) * kH + c] : 0.f;
        }
        {   // epilogue m=0 -> qs
            const int row = w * 16 + ll;
            #pragma unroll
            for (int mt = 0; mt < 4; ++mt) {
                const int c0 = mt * 16 + 4 * lq;
                const float4 bv4 = *(const float4*)&bias_s[0 * kH + c0];
                const u32x2 pk = { cvt_pk(acc[mt][0] + bv4.x, acc[mt][1] + bv4.y),
                                   cvt_pk(acc[mt][2] + bv4.z, acc[mt][3] + bv4.w) };
                *(u32x2*)(qs + row * QS + c0) = pk;
            }
        }
        __syncthreads();                        // WsB (Wk) ready for all

        // ---- m=1: K (reads WsB); stage Wv into WsA; JIT-load Wo ----
        f32x4 acc1[4];
        {
            f32x4* acc = acc1;                  // reuse macro
            QKV_MFMA(WsB);
        }
        stage_w_regs(wv_r, WsA, tid);
        float wo_r[10];
        #pragma unroll
        for (int it = 0; it < 5; ++it) {
            const int i = it * 1024 + tid;      // 5120 = 160n x 32 k-pairs
            const int n = i % 160, k = (i / 160) * 2;
            wo_r[2*it]   = (n < kC) ? Wo[k * kC + n] : 0.f;
            wo_r[2*it+1] = (n < kC) ? Wo[(k + 1) * kC + n] : 0.f;
        }
        {   // epilogue m=1 -> ks_
            const int row = w * 16 + ll;
            #pragma unroll
            for (int mt = 0; mt < 4; ++mt) {
                const int c0 = mt * 16 + 4 * lq;
                const float4 bv4 = *(const float4*)&bias_s[1 * kH + c0];
                const u32x2 pk = { cvt_pk(acc1[mt][0] + bv4.x, acc1[mt][1] + bv4.y),
                                   cvt_pk(acc1[mt][2] + bv4.z, acc1[mt][3] + bv4.w) };
                *(u32x2*)(ks_ + row * QS + c0) = pk;
            }
        }
        __syncthreads();                        // WsA (Wv) ready

        // ---- m=2: V (reads WsA); stage Wo into WsB (Wk dead) ----
        f32x4 acc2[4];
        {
            f32x4* acc = acc2;
            QKV_MFMA(WsA);
        }
        #pragma unroll
        for (int it = 0; it < 5; ++it) {
            const int i = it * 1024 + tid;
            const int n = i % 160, k = (i / 160) * 2;
            *(unsigned*)&WsB[n * WOS + (k ^ (((n >> 3) & 3) << 3))]
                = cvt_pk(wo_r[2*it], wo_r[2*it + 1]);
        }
        {   // epilogue m=2 -> vt (V stored transposed: vt[c][row])
            const int row = w * 16 + ll;
            #pragma unroll
            for (int mt = 0; mt < 4; ++mt) {
                const int c0 = mt * 16 + 4 * lq;
                const float4 bv4 = *(const float4*)&bias_s[2 * kH + c0];
                vt[(c0 + 0) * VS + row] = f2bf(acc2[mt][0] + bv4.x);
                vt[(c0 + 1) * VS + row] = f2bf(acc2[mt][1] + bv4.y);
                vt[(c0 + 2) * VS + row] = f2bf(acc2[mt][2] + bv4.z);
                vt[(c0 + 3) * VS + row] = f2bf(acc2[mt][3] + bv4.w);
            }
        }
        __syncthreads();                        // q/k/vt complete; Wo staged
    }

    // ================= attention: wave = (head, q-quarter of 64) ===========
    // Swapped QK^T (lane = q) + permlane half-exchange keeps P entirely in
    // registers; PV = 32x32x16 MFMA with B=P (col=q=lane). No P LDS at all.
    const int h = w & 3;
    const int q0 = (w >> 2) * 64;
    bf16x8 qf[2];                              // B-frags (read own q region)
    #pragma unroll
    for (int s32 = 0; s32 < 2; ++s32)
        qf[s32] = *(const bf16x8*)(qs + (q0 + s32*32 + lm) * QS + h*16 + lh*8);

    f32x16 oacc[2];                            // D: col=q=lm, row=d (regs 0-7 valid)
    #pragma unroll
    for (int s32 = 0; s32 < 2; ++s32)
        oacc[s32] = (f32x16){0.f,0.f,0.f,0.f,0.f,0.f,0.f,0.f,
                             0.f,0.f,0.f,0.f,0.f,0.f,0.f,0.f};
    float lp[2] = {0.f, 0.f};
    const int vrow = h * 16 + (lm & 15);       // lanes 16-31 dup rows (bcast, free)
    const f32x16 z16 = {0.f,0.f,0.f,0.f,0.f,0.f,0.f,0.f,
                        0.f,0.f,0.f,0.f,0.f,0.f,0.f,0.f};

    #pragma unroll 2
    for (int jb = 0; jb < 8; ++jb) {
        const int j0 = jb * 32;
        const bf16x8 kf  = *(const bf16x8*)(ks_ + (j0 + lm) * QS + h*16 + lh*8);
        // A-frags for PV: lane holds V^T row d=lm&15, k=j (lh splits j-halves)
        const bf16x8 va0 = *(const bf16x8*)(vt + vrow * VS + j0 + lh*8);
        const bf16x8 va1 = *(const bf16x8*)(vt + vrow * VS + j0 + 16 + lh*8);
        #pragma unroll
        for (int s32 = 0; s32 < 2; ++s32) {
            const f32x16 s = MFMA32(kf, qf[s32], z16);   // S^T: col=q=lm, row=j
            float sum = 0.f;
            unsigned u[8];
            #pragma unroll
            for (int g = 0; g < 4; ++g) {                // j = r + 8g + 4lh
                const float p0 = EXP2(s[4*g + 0]);       // scale folded into Wq
                const float p1 = EXP2(s[4*g + 1]);
                const float p2 = EXP2(s[4*g + 2]);
                const float p3 = EXP2(s[4*g + 3]);
                sum += (p0 + p1) + (p2 + p3);
                u[2*g]   = cvt_pk(p0, p1);
                u[2*g+1] = cvt_pk(p2, p3);
            }
            lp[s32] += sum;
            // lane±32 half-exchange -> B-frags with k=j in order (T12):
            // (reg0,reg2)=swap(u0,u2), (reg1,reg3)=swap(u1,u3); same for j+16.
            unsigned a0 = u[0], a1 = u[1], b0 = u[2], b1 = u[3];
            asm("v_permlane32_swap_b32 %0, %1" : "+v"(a0), "+v"(b0));
            asm("v_permlane32_swap_b32 %0, %1" : "+v"(a1), "+v"(b1));
            unsigned c0 = u[4], c1 = u[5], d0 = u[6], d1 = u[7];
            asm("v_permlane32_swap_b32 %0, %1" : "+v"(c0), "+v"(d0));
            asm("v_permlane32_swap_b32 %0, %1" : "+v"(c1), "+v"(d1));
            const u32x4 pb0 = { a0, a1, b0, b1 };
            const u32x4 pb1 = { c0, c1, d0, d1 };
            oacc[s32] = MFMA32(va0, __builtin_bit_cast(bf16x8, pb0), oacc[s32]);
            oacc[s32] = MFMA32(va1, __builtin_bit_cast(bf16x8, pb1), oacc[s32]);
        }
    }
    // ---- normalize + X write (row-sum is lane-local; no l_s) ----
    #pragma unroll
    for (int s32 = 0; s32 < 2; ++s32) {
        const float l2 = lp[s32] + __shfl_xor(lp[s32], 32);
        const float inv = 1.f / l2;
        const int row = q0 + s32 * 32 + lm;
        // oacc regs r=0..7 hold d = (r&3) + 8*(r>>2) + 4*lh
        const u32x2 pkA = { cvt_pk(oacc[s32][0] * inv, oacc[s32][1] * inv),
                            cvt_pk(oacc[s32][2] * inv, oacc[s32][3] * inv) };
        *(u32x2*)(qs + row * QS + h*16 + 4*lh) = pkA;
        const u32x2 pkB = { cvt_pk(oacc[s32][4] * inv, oacc[s32][5] * inv),
                            cvt_pk(oacc[s32][6] * inv, oacc[s32][7] * inv) };
        *(u32x2*)(qs + row * QS + h*16 + 8 + 4*lh) = pkB;
    }
    __syncthreads();                            // X complete; Wo already in WsB

    // ================= output projection: X[256x64] @ Wo + bo ==============
    bf16x8 xf[2];
    #pragma unroll
    for (int k2 = 0; k2 < 2; ++k2)
        xf[k2] = *(const bf16x8*)(qs + (w*16 + ll) * QS + k2*32 + lq*8);

    f32x4 po[10];
    #pragma unroll
    for (int mt = 0; mt < 10; ++mt) po[mt] = (f32x4){0.f,0.f,0.f,0.f};
    #pragma unroll
    for (int k2 = 0; k2 < 2; ++k2)
        #pragma unroll
        for (int mt = 0; mt < 10; ++mt) {
            const int n = mt * 16 + ll;
            const int key = ((n >> 3) & 3) << 3;
            const bf16x8 wf = *(const bf16x8*)(WsB + n * WOS + ((k2*32 + lq*8) ^ key));
            po[mt] = MFMA16(wf, xf[k2], po[mt]);
        }
    {
        const int row = w * 16 + ll;
        float* orow = out + ((size_t)b * 256 + row) * kC;
        #pragma unroll
        for (int mt = 0; mt < 10; ++mt) {
            const int c0 = mt * 16 + 4 * lq;
            if (mt < 9) {
                const float4 bv4 = *(const float4*)(bo + c0);
                float4 o;
                o.x = po[mt][0] + bv4.x; o.y = po[mt][1] + bv4.y;
                o.z = po[mt][2] + bv4.z; o.w = po[mt][3] + bv4.w;
                *(float4*)(orow + c0) = o;
            } else {
                #pragma unroll
                for (int r = 0; r < 4; ++r) {
                    const int c = c0 + r;
                    if (c < kC) orow[c] = po[mt][r] + bo[c];
                }
            }
        }
    }
}

extern "C" void kernel_launch(void* const* d_in, const int* in_sizes, int n_in,
                              void* d_out, int out_size, void* d_ws, size_t ws_size,
                              hipStream_t stream) {
    const float* pose    = (const float*)d_in[0];
    const float* bpm_emb = (const float*)d_in[1];
    const float* Wq = (const float*)d_in[2];  const float* bq = (const float*)d_in[3];
    const float* Wk = (const float*)d_in[4];  const float* bk = (const float*)d_in[5];
    const float* Wv = (const float*)d_in[6];  const float* bv = (const float*)d_in[7];
    const float* Wb = (const float*)d_in[8];  const float* bb = (const float*)d_in[9];
    const float* Wo = (const float*)d_in[10]; const float* bo = (const float*)d_in[11];
    float* out = (float*)d_out;

    fused_kernel<<<256, 1024, 0, stream>>>(
        pose, bpm_emb, Wq, bq, Wk, bk, Wv, bv, Wb, bb, Wo, bo, out);
}